// Round 26
// baseline (105.341 us; speedup 1.0000x reference)
//
#include <hip/hip_runtime.h>
#include <hip/hip_bf16.h>

#define CS 384
#define CH 32
#define CZ 128
#define LL 384
#define NL 1536   // N*L
#define EPS 1e-5f

typedef float v4f __attribute__((ext_vector_type(4)));
typedef short s8v __attribute__((ext_vector_type(8)));          // 8 bf16 (MFMA A/B frag)
typedef unsigned short u8s __attribute__((ext_vector_type(8))); // 8 bf16 bits

static __device__ __forceinline__ unsigned short f2bf(float x) {
    unsigned int b = __float_as_uint(x);
    b += 0x7FFFu + ((b >> 16) & 1u);        // round-to-nearest-even
    return (unsigned short)(b >> 16);
}
static __device__ __forceinline__ v4f bf4_to_f4(ushort4 h) {
    v4f r;
    r.x = __uint_as_float((unsigned)h.x << 16);
    r.y = __uint_as_float((unsigned)h.y << 16);
    r.z = __uint_as_float((unsigned)h.z << 16);
    r.w = __uint_as_float((unsigned)h.w << 16);
    return r;
}

// ---------------- Kernel 1: LN + B = sn@W2+b2 -> Bf frags; Wo -> bf16 --------
// (identical to R21/R23)
__global__ __launch_bounds__(256) void k_bf(
    const float* __restrict__ s, const float* __restrict__ g, const float* __restrict__ be,
    const float* __restrict__ W2, const float* __restrict__ pb2,
    const float* __restrict__ Wo,
    unsigned short* __restrict__ BfG, unsigned short* __restrict__ Wob)
{
    const int r0 = blockIdx.x * 4;
    const int t  = threadIdx.x;

    {
        const int idx = blockIdx.x * 256 + t;
        if (idx < (CH * CH * CZ) / 4) {
            const v4f v = ((const v4f*)Wo)[idx];
            ushort4 h;
            h.x = f2bf(v.x); h.y = f2bf(v.y); h.z = f2bf(v.z); h.w = f2bf(v.w);
            ((ushort4*)Wob)[idx] = h;
        }
    }

    __shared__ float sn[4][392];
    __shared__ float part[4][2][32];

    {
        const int w = t >> 6, lane = t & 63;
        const float* srow = s + (size_t)(r0 + w) * CS;
        float x[6];
        #pragma unroll
        for (int k = 0; k < 6; ++k) x[k] = srow[lane + k * 64];
        float p = x[0] + x[1] + x[2] + x[3] + x[4] + x[5];
        #pragma unroll
        for (int m = 1; m < 64; m <<= 1) p += __shfl_xor(p, m);
        const float mu = p * (1.0f / CS);
        float q = 0.f;
        #pragma unroll
        for (int k = 0; k < 6; ++k) { float d = x[k] - mu; q += d * d; }
        #pragma unroll
        for (int m = 1; m < 64; m <<= 1) q += __shfl_xor(q, m);
        const float rstd = rsqrtf(q * (1.0f / CS) + EPS);
        #pragma unroll
        for (int k = 0; k < 6; ++k) {
            const int c = lane + k * 64;
            sn[w][c] = (x[k] - mu) * rstd * g[c] + be[c];
        }
    }
    __syncthreads();

    {
        const int h = t & 31, ch = (t >> 5) & 1, rw = t >> 6;
        const float* snr = sn[rw];
        float acc = 0.f;
        const int c0 = ch * 192;
        #pragma unroll 8
        for (int c = c0; c < c0 + 192; ++c)
            acc += snr[c] * W2[c * CH + h];
        part[rw][ch][h] = acc;
    }
    __syncthreads();

    if (t < 128) {
        const int rw = t >> 5, h = t & 31;
        const float v = part[rw][0][h] + part[rw][1][h] + pb2[h];
        const int row = r0 + rw;
        const int n = row / LL, jr = row % LL;
        const int jt = jr >> 4, l16 = jr & 15;
        BfG[(((size_t)(n * 24 + jt)) * 64 + l16 + 16 * (h >> 3)) * 8 + (h & 7)] = f2bf(v);
    }
}

// ---------------- Kernel 2: WAVE-PRIVATE end-to-end pipeline -----------------
// 2-wave blocks, grid 768 (all resident). Wave w owns row r0+w completely:
// LN -> a-matvec (shfl combine) -> M = a@Wob -> swizzled MsubT (wave-private)
// -> mf rebuild -> 24 jt of MFMA + bounce + contiguous stores.
// ZERO __syncthreads: no vmcnt drains; waves drift so prep overlaps drains.
__global__ __launch_bounds__(128) void k_out_f(
    const float* __restrict__ s, const float* __restrict__ g, const float* __restrict__ be,
    const float* __restrict__ W1, const float* __restrict__ pb1,
    const unsigned short* __restrict__ Wob, const unsigned short* __restrict__ BfG,
    const float* __restrict__ bo, float* __restrict__ out)
{
    const int r0 = blockIdx.x * 2;
    const int n  = r0 / LL;
    const int t  = threadIdx.x;
    const int l  = t & 63, w = t >> 6;
    const int r  = r0 + w;
    const int g2 = l >> 4, c16 = l & 15;
    const int li = l & 31, hi2 = l >> 5;

    __shared__ __align__(16) unsigned short MsubT[2][4096];  // 16 KB, wave-private
    __shared__ __align__(16) char ovl[2][8192];               // 16 KB: sn overlay / bounce
    __shared__ float aW[2][32];                               // 256 B

    // ---- hoisted VMEM: af[24] + bov ride under all of prep ----
    s8v af[24];
    {
        const s8v* Bfn = (const s8v*)(BfG + (size_t)n * 24 * 64 * 8);
        #pragma unroll
        for (int i = 0; i < 24; ++i) af[i] = Bfn[i * 64 + l];
    }
    v4f bov[8];
    #pragma unroll
    for (int zt = 0; zt < 8; ++zt) bov[zt] = *(const v4f*)(bo + zt * 16 + g2 * 4);

    float* sn = (float*)ovl[w];

    // ---- LN of row r (wave-wide) ----
    {
        const float* srow = s + (size_t)r * CS;
        float x[6];
        #pragma unroll
        for (int k = 0; k < 6; ++k) x[k] = srow[l + k * 64];
        float p = x[0] + x[1] + x[2] + x[3] + x[4] + x[5];
        #pragma unroll
        for (int m = 1; m < 64; m <<= 1) p += __shfl_xor(p, m);
        const float mu = p * (1.0f / CS);
        float q = 0.f;
        #pragma unroll
        for (int k = 0; k < 6; ++k) { float d = x[k] - mu; q += d * d; }
        #pragma unroll
        for (int m = 1; m < 64; m <<= 1) q += __shfl_xor(q, m);
        const float rstd = rsqrtf(q * (1.0f / CS) + EPS);
        #pragma unroll
        for (int k = 0; k < 6; ++k) {
            const int c = l + k * 64;
            sn[c] = (x[k] - mu) * rstd * g[c] + be[c];
        }
    }
    asm volatile("s_waitcnt lgkmcnt(0)" ::: "memory");   // sn visible to own wave

    // ---- a = sn@W1 + b1 (c-halves per lane, shfl_xor(32) combine) ----
    {
        const int h = l & 31, half = l >> 5;
        float acc = 0.f;
        const int c0 = half * 192;
        #pragma unroll 8
        for (int c = c0; c < c0 + 192; ++c)
            acc += sn[c] * W1[c * CH + h];
        acc += __shfl_xor(acc, 32);
        if (l < 32) aW[w][l] = acc + pb1[l];
    }
    asm volatile("s_waitcnt lgkmcnt(0)" ::: "memory");

    // aw -> registers (32 broadcast reads, once)
    float aw[CH];
    #pragma unroll
    for (int c = 0; c < CH; ++c) aw[c] = aW[w][c];

    // ---- M = a @ Wob -> MsubT (transposed, XOR-swizzled, wave-private) ----
    {
        const ushort4* Wo4 = (const ushort4*)Wob;   // 1024 ushort4 per c-row
        #pragma unroll
        for (int it = 0; it < 16; ++it) {
            const int col = l + it * 64;            // col = d*32 + zq
            const int d = col >> 5, zq = col & 31;
            v4f a0 = (v4f)(0.f);
            #pragma unroll 8
            for (int c = 0; c < CH; ++c)
                a0 += aw[c] * bf4_to_f4(Wo4[(size_t)c * 1024 + col]);
            const int bsw = ((d >> 3) ^ (zq & 3)) * 8 + (d & 7);
            #pragma unroll
            for (int j = 0; j < 4; ++j)
                MsubT[w][(zq * 4 + j) * 32 + bsw] = f2bf(a0[j]);
        }
    }
    asm volatile("s_waitcnt lgkmcnt(0)" ::: "memory");   // MsubT visible (same wave)

    // ---- mf rebuild (one b128 read per zt, swizzled block) ----
    s8v mf[8];
    {
        const int rblk = (g2 ^ ((c16 >> 2) & 3)) * 8;
        #pragma unroll
        for (int zt = 0; zt < 8; ++zt)
            mf[zt] = *(const s8v*)(&MsubT[w][(zt * 16 + c16) * 32 + rblk]);
    }

    // ---- out: all 24 jt (MFMA + bounce + contiguous 1024-B stores) ----
    char* myl = ovl[w];                              // sn is dead; reuse as bounce
    v4f* outv = (v4f*)(out + (size_t)r * LL * CZ);   // 32 v4f per j-row

    for (int jt = 0; jt < 24; ++jt) {
        #pragma unroll
        for (int zt = 0; zt < 8; ++zt) {
            v4f d = __builtin_amdgcn_mfma_f32_16x16x32_bf16(mf[zt], af[jt], (v4f)(0.f), 0, 0, 0);
            d += bov[zt];
            const int byte = (c16 << 9) + (((zt << 6) + (g2 << 4)) ^ ((c16 & 7) << 4));
            *(v4f*)(myl + byte) = d;
        }
        asm volatile("s_waitcnt lgkmcnt(0)" ::: "memory");

        #pragma unroll
        for (int i2 = 0; i2 < 8; ++i2) {
            const int rw2 = 2 * i2 + hi2;
            const int byte = (rw2 << 9) + (((li << 4)) ^ ((rw2 & 7) << 4));
            const v4f v = *(const v4f*)(myl + byte);
            outv[(size_t)(jt * 16 + rw2) * 32 + li] = v;
        }
    }
}

extern "C" void kernel_launch(void* const* d_in, const int* in_sizes, int n_in,
                              void* d_out, int out_size, void* d_ws, size_t ws_size,
                              hipStream_t stream) {
    const float* s  = (const float*)d_in[0];
    const float* g  = (const float*)d_in[1];
    const float* be = (const float*)d_in[2];
    const float* W1 = (const float*)d_in[3];
    const float* b1 = (const float*)d_in[4];
    const float* W2 = (const float*)d_in[5];
    const float* b2 = (const float*)d_in[6];
    const float* Wo = (const float*)d_in[7];
    const float* bo = (const float*)d_in[8];
    float* out = (float*)d_out;

    // ws layout (bytes): Bf bf16 [0, 98304) | Wob bf16 [98304, 98304+262144)
    if (ws_size < 98304u + 262144u) return;  // fail visibly, no UB
    unsigned short* Bf  = (unsigned short*)d_ws;
    unsigned short* Wob = (unsigned short*)((char*)d_ws + 98304);

    k_bf   <<<NL / 4, 256, 0, stream>>>(s, g, be, W2, b2, Wo, Bf, Wob);
    k_out_f<<<NL / 2, 128, 0, stream>>>(s, g, be, W1, b1, Wob, Bf, bo, out);
}